// Round 13
// baseline (28.181 us; speedup 1.0000x reference)
//
#include <hip/hip_runtime.h>

#define C 256
#define HW 81
#define PITCH 292   // ushorts per pixel row: [4 pad][256 ch][32 pad] (even dword pitch)
#define PITCHD 146  // dwords per pixel row; 146%32=18 -> gather tap bases ~4-apart
#define ZROW 81     // zeroed row index for invalid gather taps

typedef __fp16 h2 __attribute__((ext_vector_type(2)));  // matches builtin V2h

__device__ __forceinline__ float us2f(unsigned short u) {  // f16 bits -> f32
  union { unsigned short s; __fp16 h; } c; c.s = u; return (float)c.h;
}
__device__ __forceinline__ float lo_h(unsigned int d) {
  union { unsigned int i; h2 h; } c; c.i = d; return (float)c.h.x;
}
__device__ __forceinline__ float hi_h(unsigned int d) {
  union { unsigned int i; h2 h; } c; c.i = d; return (float)c.h.y;
}
__device__ __forceinline__ unsigned int pkh2(float a, float b) {  // 1x cvt_pkrtz
  union { h2 h; unsigned int i; } c;
  c.h = __builtin_amdgcn_cvt_pkrtz(a, b);
  return c.i;
}
__device__ __forceinline__ h2 as_h2(unsigned int d) {
  union { unsigned int i; h2 h; } c; c.i = d; return c.h;
}
__device__ __forceinline__ float dot2(unsigned int a, unsigned int b, float c) {
#if __has_builtin(__builtin_amdgcn_fdot2)
  return __builtin_amdgcn_fdot2(as_h2(a), as_h2(b), c, false);
#else
  h2 x = as_h2(a), y = as_h2(b);
  return fmaf((float)x.y, (float)y.y, fmaf((float)x.x, (float)y.x, c));
#endif
}
__device__ __forceinline__ float exp2_fast(float x) {
#if __has_builtin(__builtin_amdgcn_exp2f)
  return __builtin_amdgcn_exp2f(x);
#else
  return __expf(x * 0.6931471805599453f);
#endif
}

// ---------------------------------------------------------------------------
// R13: DIAGNOSTIC PROBE on the R10 base (best, 25.58us). Phases 1a and 1b are
// executed TWICE; each shadow starts with a memory clobber (forces genuine
// LDS re-reads, defeats CSE) and sinks results into asm "v" constraints
// (no stores -> no races; shadows only READ xT). Output identical to R10.
// Delta(dur) vs 25.58us isolates phases 1a+1b marginal wall cost
// (~330 instr/thread):
//   >=1.1us: issue-priced -> R14 = width-8 1a diet (quantified).
//   0.4-1.1: partially hidden -> small upside only.
//   <0.4us: latency-hidden -> remaining ~17us is load/barrier/launch floor;
//           declare the structural constraint with this evidence.
// ---------------------------------------------------------------------------
__global__ __launch_bounds__(1024) void semca_fused(
    const float* __restrict__ x, const float* __restrict__ wk,
    const float* __restrict__ bk, const float* __restrict__ w1,
    const float* __restrict__ gamma, const float* __restrict__ beta,
    const float* __restrict__ mean, const float* __restrict__ var,
    const float* __restrict__ w2, const float* __restrict__ b2,
    const float* __restrict__ wv, const float* __restrict__ bv,
    float* __restrict__ out) {
  __shared__ unsigned short xT[82 * PITCH];   // 47,888 B (row 81 = zeros), f16
  __shared__ unsigned short k1T[82 * PITCH];  // 47,888 B (row 81 = zeros), f16
  __shared__ unsigned short vT[18 * PITCH];   // 10,512 B, f16
  __shared__ unsigned short pixtab[228];      //    456 B (premultiplied by PITCH)
  __shared__ float2 bnf[225];                 //  1,800 B
  __shared__ unsigned int w1p[225 * 12];      // 10,800 B half2 pairs, 48B/row
  __shared__ unsigned int w2p[225 * 4];       //  3,600 B half2 o-pairs (16B/row)
  __shared__ uint2 wkp[81 * 3];               //  1,944 B wk half2: 6 dwords/pixel

  const int blk = blockIdx.x;
  const int b = (blk & 7) * 16 + ((blk >> 3) & 15);  // XCD-paired, bijective
  const int s = blk >> 7;
  const int tid = threadIdx.x;
  const float* xb = x + (size_t)b * (C * HW);

  unsigned int* xTd = (unsigned int*)xT;
  unsigned int* k1Td = (unsigned int*)k1T;
  unsigned int* vTd = (unsigned int*)vT;
  unsigned int* wkpd = (unsigned int*)wkp;

  // ---- phase 0a: issue ALL x loads first (registers), incremental walk
  float xe[11], xo[11];
  int adr[11];
  {
    int chp = tid / HW;            // single division
    int p = tid - chp * HW;
#pragma unroll
    for (int rep = 0; rep < 10; ++rep) {
      const float* base = xb + (2 * chp) * HW + p;
      xe[rep] = base[0];
      xo[rep] = base[HW];
      adr[rep] = PITCHD * p + 2 + chp;
      chp += 12;                   // advance f by 1024 = 12*81 + 52
      p += 52;
      if (p >= HW) { p -= HW; chp += 1; }
    }
    if (tid < 128) {               // tail item f = 10240 + tid
      int f = 10240 + tid;
      int c2 = f / HW, p2 = f - c2 * HW;
      xe[10] = xb[2 * c2 * HW + p2];
      xo[10] = xb[(2 * c2 + 1) * HW + p2];
      adr[10] = PITCHD * p2 + 2 + c2;
    }
  }

  // ---- phase 0b: independent work under the load shadow
  for (int t = tid; t < 810; t += 1024) {  // x channel-pad zeros
    int p = t / 10, k2 = t - (t / 10) * 10;
    xT[p * PITCH + ((k2 < 4) ? k2 : (256 + k2))] = 0;
  }
  if (tid < PITCHD) {                      // zero row 81 of xT and k1T
    xTd[PITCHD * ZROW + tid] = 0;
    k1Td[PITCHD * ZROW + tid] = 0;
  }
  for (int t = tid; t < 225; t += 1024) {  // pixtab (premul) + folded BN
    int g = t / 9, tap = t - (t / 9) * 9;
    int kh = tap / 3, kw = tap - kh * 3;
    int h = kh * 5 + g / 5, w = kw * 5 + (g - (g / 5) * 5);
    pixtab[t] = (h < 9 && w < 9) ? (unsigned short)((h * 9 + w) * PITCH)
                                 : (unsigned short)(ZROW * PITCH);
    float inv = gamma[t] * rsqrtf(var[t] + 1e-5f);
    bnf[t] = make_float2(inv, beta[t] - mean[t] * inv);
  }
  for (int t = tid; t < 2025; t += 1024) {  // w1 packed pairs (x-tap, k1-tap)
    int m = t / 9, q = t - m * 9;
    w1p[m * 12 + q] = pkh2(w1[m * 18 + q], w1[m * 18 + 9 + q]);
  }
  if (tid < 900) {                          // w2 packed o-pairs (o=0..7)
    int m = tid >> 2, j = tid & 3;
    w2p[m * 4 + j] = pkh2(w2[m * 9 + 2 * j], w2[m * 9 + 2 * j + 1]);
  }
  if (tid < 486) {                          // wk packed pairs + tails
    int m = tid / 6, j = tid - (tid / 6) * 6;
    const float* wr = wk + m * 9;
    unsigned int v;
    if (j < 4)       v = pkh2(wr[2 * j], wr[2 * j + 1]);
    else if (j == 4) v = pkh2(wr[8], 0.f);
    else             v = pkh2(0.f, wr[8]);
    wkpd[m * 6 + j] = v;
  }

  // hoisted phase-1b weights: chv fixed per thread -> registers
  const int chv = tid & 127;
  float wv_e[9], wv_o[9];
#pragma unroll
  for (int t = 0; t < 9; ++t) {
    wv_e[t] = wv[(2 * chv) * 9 + t];
    wv_o[t] = wv[(2 * chv + 1) * 9 + t];
  }
  const float bv_e = bv[2 * chv], bv_o = bv[2 * chv + 1];

  // ---- phase 0c: pack (f16) + LDS write (single drain of the x loads)
#pragma unroll
  for (int rep = 0; rep < 10; ++rep) xTd[adr[rep]] = pkh2(xe[rep], xo[rep]);
  if (tid < 128) xTd[adr[10]] = pkh2(xe[10], xo[10]);

  __syncthreads();

  // ---- phase 1a: k1[p][ch] = sum_j x[p][ch+j-4]*wk[p][j] + bk[p]
  {
    auto k1fn = [&](int f, bool shadow) {
      int p = __builtin_amdgcn_readfirstlane(f >> 6);
      int u = f & 63;  // channel quad index
      const uint2* wrow2 = (const uint2*)(xTd + PITCHD * p);
      uint2 q0 = wrow2[u], q1 = wrow2[u + 1], q2 = wrow2[u + 2];
      unsigned int D0 = q0.x, D1 = q0.y, D2 = q1.x, D3 = q1.y,
                   D4 = q2.x, D5 = q2.y;
      unsigned int A0 = (D0 >> 16) | (D1 << 16);
      unsigned int A1 = (D1 >> 16) | (D2 << 16);
      unsigned int A2 = (D2 >> 16) | (D3 << 16);
      unsigned int A3 = (D3 >> 16) | (D4 << 16);
      unsigned int A4 = (D4 >> 16) | (D5 << 16);
      const uint2* wkq = wkp + p * 3;
      uint2 wa = wkq[0], wb = wkq[1], wc = wkq[2];
      float bkp = bk[p];
      float c0 = dot2(D0, wa.x, dot2(D1, wa.y, dot2(D2, wb.x,
                 dot2(D3, wb.y, dot2(D4, wc.x, bkp)))));
      float c1 = dot2(A0, wa.x, dot2(A1, wa.y, dot2(A2, wb.x,
                 dot2(A3, wb.y, dot2(D4, wc.y, bkp)))));
      float c2 = dot2(D1, wa.x, dot2(D2, wa.y, dot2(D3, wb.x,
                 dot2(D4, wb.y, dot2(D5, wc.x, bkp)))));
      float c3 = dot2(A1, wa.x, dot2(A2, wa.y, dot2(A3, wb.x,
                 dot2(A4, wb.y, dot2(D5, wc.y, bkp)))));
      if (!shadow) {
        *(uint2*)(k1Td + PITCHD * p + 2 + 2 * u) =
            make_uint2(pkh2(c0, c1), pkh2(c2, c3));
      } else {
        asm volatile("" :: "v"(c0), "v"(c1), "v"(c2), "v"(c3));
      }
    };
#pragma unroll
    for (int rep = 0; rep < 5; ++rep) k1fn(tid + rep * 1024, false);
    if (tid < 64) k1fn(5120 + tid, false);
    // ---- SHADOW 1a (probe): clobber forces re-reads; results sunk
    asm volatile("" ::: "memory");
#pragma unroll
    for (int rep = 0; rep < 5; ++rep) k1fn(tid + rep * 1024, true);
    if (tid < 64) k1fn(5120 + tid, true);
  }

  // ---- phase 1b: v (3x3 depthwise) at the 18 pixels this half needs
  {
    auto vfn = [&](int f, bool shadow) {
      int e = __builtin_amdgcn_readfirstlane(f >> 7);  // 0..17 uniform
      int r0 = e / 6;
      int i = s * 3 + r0;  // v-pixel row 0..5
      int j = e - r0 * 6;  // v-pixel col 0..5
      float a_e = bv_e, a_o = bv_o;
#pragma unroll
      for (int di = 0; di < 3; ++di) {
        int ii = i + di - 1;
        if (ii < 0) continue;  // ii <= 6 < 9 always
#pragma unroll
        for (int dj = 0; dj < 3; ++dj) {
          int jj = j + dj - 1;
          if (jj < 0) continue;  // jj <= 6 < 9 always
          unsigned int d = xTd[PITCHD * (ii * 9 + jj) + 2 + chv];
          int t = di * 3 + dj;
          a_e = fmaf(lo_h(d), wv_e[t], a_e);
          a_o = fmaf(hi_h(d), wv_o[t], a_o);
        }
      }
      if (!shadow) {
        vTd[PITCHD * e + 2 + chv] = pkh2(a_e, a_o);
      } else {
        asm volatile("" :: "v"(a_e), "v"(a_o));
      }
    };
#pragma unroll
    for (int rep = 0; rep < 2; ++rep) vfn(tid + rep * 1024, false);
    if (tid < 256) vfn(2048 + tid, false);
    // ---- SHADOW 1b (probe)
    asm volatile("" ::: "memory");
#pragma unroll
    for (int rep = 0; rep < 2; ++rep) vfn(tid + rep * 1024, true);
    if (tid < 256) vfn(2048 + tid, true);
  }
  if (tid < 180) {  // vT channel-pad zeros
    int e = tid / 10, k2 = tid - (tid / 10) * 10;
    vT[e * PITCH + ((k2 < 4) ? k2 : (256 + k2))] = 0;
  }
  __syncthreads();

  // ---- phase 2: 15 deduped instances; 4 slots x 4 unrolled iterations
  const int s4 = tid >> 8;  // slot 0..3 (wave-uniform)
  const int ch = tid & 255;
  const int ci0 = ch / 9;
  const int tap0 = ch - ci0 * 9;
  float* outb = out + ((size_t)b * C + ch) * HW;

  // per-lane gather walk is instance-invariant
  int tq[9], cq[9];
  {
    int ci = ci0, tap = tap0;
#pragma unroll
    for (int q = 0; q < 9; ++q) {
      tq[q] = tap;
      cq[q] = 4 + ci;
      tap += 4;
      ci += 28;
      if (tap >= 9) { tap -= 9; ci += 1; }
    }
  }

#define PV_STORE(OH, OW)                                                   \
  do {                                                                     \
    int e_ = gh_i * 6 + ((OW)-3);                                          \
    const unsigned short* vrow_ = vT + e_ * PITCH;                         \
    float acc_ = 0.f;                                                      \
    _Pragma("unroll") for (int d_ = 0; d_ < 9; ++d_) acc_ =                \
        fmaf(a2[d_], us2f(vrow_[ch + d_]), acc_);                          \
    if ((OH) < 6 && (OW) < 6)                                              \
      acc_ = fmaf(acc_, inv_s,                                             \
                  us2f(k1T[(((OH) + 3) * 9 + ((OW) + 3)) * PITCH + 4 + ch])); \
    else                                                                   \
      acc_ *= inv_s;                                                       \
    if (valid_inst) outb[(OH)*9 + (OW)] = acc_;                            \
  } while (0)

#pragma unroll
  for (int k = 0; k < 4; ++k) {
    int idx = s4 * 4 + k;
    const bool valid_inst = (idx < 15);
    if (!valid_inst) idx = 14;  // dummy recomputes a real instance, no store
    int gh_i = idx / 5, gw_i = idx - (idx / 5) * 5;
    int oh = (s ? 6 : 3) + gh_i;
    int gh = s ? ((gh_i + 4) % 5) : (gh_i + 1);
    int g9 = __builtin_amdgcn_readfirstlane((gh * 5 + gw_i) * 9);

    // kq gather -> packed half2 (x_q, k1_q): 2 u16 reads + 1 lshl_or per q
    unsigned int kqp[9];
#pragma unroll
    for (int q = 0; q < 9; ++q) {
      int off = (int)pixtab[g9 + tq[q]] + cq[q];
      unsigned int xv = xT[off], kv = k1T[off];
      kqp[q] = xv | (kv << 16);
    }

    __builtin_amdgcn_s_setprio(1);
    // w1 (packed pairs, fdot2) -> folded BN -> ReLU
    float r[9];
#pragma unroll
    for (int o = 0; o < 9; ++o) {
      int m = g9 + o;
      const unsigned int* wp = w1p + m * 12;
      float a = 0.f;
#pragma unroll
      for (int q = 0; q < 9; ++q) a = dot2(kqp[q], wp[q], a);
      float2 bn = bnf[m];
      a = fmaf(a, bn.x, bn.y);
      r[o] = fmaxf(a, 0.f);
    }

    // w2 (packed o-pairs, fdot2) + b2 -> softmax (registers)
    unsigned int rp[4];
#pragma unroll
    for (int j = 0; j < 4; ++j) rp[j] = pkh2(r[2 * j], r[2 * j + 1]);
    float a2[9], mx = -1e30f;
#pragma unroll
    for (int d = 0; d < 9; ++d) {
      int m = g9 + d;
      const unsigned int* wq = w2p + m * 4;
      float a = b2[m];
#pragma unroll
      for (int j = 0; j < 4; ++j) a = dot2(rp[j], wq[j], a);
      a = fmaf(w2[m * 9 + 8], r[8], a);
      a2[d] = a;
      mx = fmaxf(mx, a);
    }
    const float L2E = 1.44269504f;
    float nmL = mx * -L2E;
    float ssum = 0.f;
#pragma unroll
    for (int d = 0; d < 9; ++d) {
      a2[d] = exp2_fast(fmaf(a2[d], L2E, nmL));
      ssum += a2[d];
    }
    float inv_s = __builtin_amdgcn_rcpf(ssum);
    __builtin_amdgcn_s_setprio(0);

    // PV + k1-add + store; gw==1 serves both ow=3 and ow=8
    int ow0 = (gw_i == 0) ? 7 : (gw_i + 2);
    PV_STORE(oh, ow0);
    if (gw_i == 1) PV_STORE(oh, 8);
  }
#undef PV_STORE

  // ---- epilogue: non-PV output pixels
  if (s == 0) {
    if (s4 < 3) {
      int oh = s4;  // rows 0..2: k1 where ow<6, else 0
#pragma unroll
      for (int ow = 0; ow < 9; ++ow) {
        float v2 = 0.f;
        if (ow < 6)
          v2 = us2f(k1T[((oh + 3) * 9 + (ow + 3)) * PITCH + 4 + ch]);
        outb[oh * 9 + ow] = v2;
      }
    } else {
      // rows 3..5, cols 0..2: k1-only
#pragma unroll
      for (int r0 = 0; r0 < 3; ++r0) {
        int oh = 3 + r0;
#pragma unroll
        for (int ow = 0; ow < 3; ++ow)
          outb[oh * 9 + ow] =
              us2f(k1T[((oh + 3) * 9 + (ow + 3)) * PITCH + 4 + ch]);
      }
    }
  } else if (s4 < 3) {
    int oh = 6 + s4;  // rows 6..8, cols 0..2: zero
    outb[oh * 9 + 0] = 0.f;
    outb[oh * 9 + 1] = 0.f;
    outb[oh * 9 + 2] = 0.f;
  }
}

extern "C" void kernel_launch(void* const* d_in, const int* in_sizes, int n_in,
                              void* d_out, int out_size, void* d_ws, size_t ws_size,
                              hipStream_t stream) {
  const float* x     = (const float*)d_in[0];
  const float* wk    = (const float*)d_in[1];
  const float* bk    = (const float*)d_in[2];
  const float* w1    = (const float*)d_in[3];
  const float* gamma = (const float*)d_in[4];
  const float* beta  = (const float*)d_in[5];
  const float* mean  = (const float*)d_in[6];
  const float* var   = (const float*)d_in[7];
  const float* w2    = (const float*)d_in[8];
  const float* b2    = (const float*)d_in[9];
  const float* wv    = (const float*)d_in[10];
  const float* bv    = (const float*)d_in[11];
  float* out = (float*)d_out;

  hipLaunchKernelGGL(semca_fused, dim3(256), dim3(1024), 0, stream,
                     x, wk, bk, w1, gamma, beta, mean, var, w2, b2, wv, bv, out);
}

// Round 14
// 25.265 us; speedup vs baseline: 1.1154x; 1.1154x over previous
//
#include <hip/hip_runtime.h>

#define C 256
#define HW 81
#define PITCH 292   // ushorts per pixel row: [4 pad][256 ch][32 pad] (even dword pitch)
#define PITCHD 146  // dwords per pixel row; 146%32=18 -> gather tap bases ~4-apart
#define ZROW 81     // zeroed row index for invalid gather taps

typedef __fp16 h2 __attribute__((ext_vector_type(2)));  // matches builtin V2h

__device__ __forceinline__ float us2f(unsigned short u) {  // f16 bits -> f32
  union { unsigned short s; __fp16 h; } c; c.s = u; return (float)c.h;
}
__device__ __forceinline__ float lo_h(unsigned int d) {
  union { unsigned int i; h2 h; } c; c.i = d; return (float)c.h.x;
}
__device__ __forceinline__ float hi_h(unsigned int d) {
  union { unsigned int i; h2 h; } c; c.i = d; return (float)c.h.y;
}
__device__ __forceinline__ unsigned int pkh2(float a, float b) {  // 1x cvt_pkrtz
  union { h2 h; unsigned int i; } c;
  c.h = __builtin_amdgcn_cvt_pkrtz(a, b);
  return c.i;
}
__device__ __forceinline__ h2 as_h2(unsigned int d) {
  union { unsigned int i; h2 h; } c; c.i = d; return c.h;
}
__device__ __forceinline__ float dot2(unsigned int a, unsigned int b, float c) {
#if __has_builtin(__builtin_amdgcn_fdot2)
  return __builtin_amdgcn_fdot2(as_h2(a), as_h2(b), c, false);
#else
  h2 x = as_h2(a), y = as_h2(b);
  return fmaf((float)x.y, (float)y.y, fmaf((float)x.x, (float)y.x, c));
#endif
}
__device__ __forceinline__ float exp2_fast(float x) {
#if __has_builtin(__builtin_amdgcn_exp2f)
  return __builtin_amdgcn_exp2f(x);
#else
  return __expf(x * 0.6931471805599453f);
#endif
}

// ---------------------------------------------------------------------------
// Fully fused SeMCA. Block = (b, s): s=0 -> output rows 0..5, s=1 -> rows 6..8.
// 1024 threads = 4 instance-slots x 256 channels. 2 barriers.
// R14 = R10 base (best, 25.58us) with a phase-1a diet (R13 probe proved 1a+1b
// are issue-priced at ~8ns/instr):
//  - width-8 1a: 8 channels per call from 8 window dwords (4x ds_read_b64,
//    8B-aligned any row) + 7 alignbits + 40 fdot2 + 2 b64 writes. Identical
//    dot pairing to width-4 -> bit-identical numerics.
//  - row-cut: s=0 computes k1 rows 1..8 only (row 0 never read by s=0's
//    gather {1,2,3,6,7,8}, PV rows 6..8, epilogue rows 3..8); s=1 computes
//    rows {0,1,4,5,6} only (gather-only consumer). Uncomputed rows provably
//    never read; ZROW still zeroed.
//  - p is per-lane in 1a now (no readfirstlane); bk/wkp reads are 2-addr
//    broadcast-friendly.
// Everything else byte-identical to R10.
// ---------------------------------------------------------------------------
__global__ __launch_bounds__(1024) void semca_fused(
    const float* __restrict__ x, const float* __restrict__ wk,
    const float* __restrict__ bk, const float* __restrict__ w1,
    const float* __restrict__ gamma, const float* __restrict__ beta,
    const float* __restrict__ mean, const float* __restrict__ var,
    const float* __restrict__ w2, const float* __restrict__ b2,
    const float* __restrict__ wv, const float* __restrict__ bv,
    float* __restrict__ out) {
  __shared__ unsigned short xT[82 * PITCH];   // 47,888 B (row 81 = zeros), f16
  __shared__ unsigned short k1T[82 * PITCH];  // 47,888 B (row 81 = zeros), f16
  __shared__ unsigned short vT[18 * PITCH];   // 10,512 B, f16
  __shared__ unsigned short pixtab[228];      //    456 B (premultiplied by PITCH)
  __shared__ float2 bnf[225];                 //  1,800 B
  __shared__ unsigned int w1p[225 * 12];      // 10,800 B half2 pairs, 48B/row
  __shared__ unsigned int w2p[225 * 4];       //  3,600 B half2 o-pairs (16B/row)
  __shared__ uint2 wkp[81 * 3];               //  1,944 B wk half2: 6 dwords/pixel

  const int blk = blockIdx.x;
  const int b = (blk & 7) * 16 + ((blk >> 3) & 15);  // XCD-paired, bijective
  const int s = blk >> 7;
  const int tid = threadIdx.x;
  const float* xb = x + (size_t)b * (C * HW);

  unsigned int* xTd = (unsigned int*)xT;
  unsigned int* k1Td = (unsigned int*)k1T;
  unsigned int* vTd = (unsigned int*)vT;
  unsigned int* wkpd = (unsigned int*)wkp;

  // ---- phase 0a: issue ALL x loads first (registers), incremental walk
  float xe[11], xo[11];
  int adr[11];
  {
    int chp = tid / HW;            // single division
    int p = tid - chp * HW;
#pragma unroll
    for (int rep = 0; rep < 10; ++rep) {
      const float* base = xb + (2 * chp) * HW + p;
      xe[rep] = base[0];
      xo[rep] = base[HW];
      adr[rep] = PITCHD * p + 2 + chp;
      chp += 12;                   // advance f by 1024 = 12*81 + 52
      p += 52;
      if (p >= HW) { p -= HW; chp += 1; }
    }
    if (tid < 128) {               // tail item f = 10240 + tid
      int f = 10240 + tid;
      int c2 = f / HW, p2 = f - c2 * HW;
      xe[10] = xb[2 * c2 * HW + p2];
      xo[10] = xb[(2 * c2 + 1) * HW + p2];
      adr[10] = PITCHD * p2 + 2 + c2;
    }
  }

  // ---- phase 0b: independent work under the load shadow
  for (int t = tid; t < 810; t += 1024) {  // x channel-pad zeros
    int p = t / 10, k2 = t - (t / 10) * 10;
    xT[p * PITCH + ((k2 < 4) ? k2 : (256 + k2))] = 0;
  }
  if (tid < PITCHD) {                      // zero row 81 of xT and k1T
    xTd[PITCHD * ZROW + tid] = 0;
    k1Td[PITCHD * ZROW + tid] = 0;
  }
  for (int t = tid; t < 225; t += 1024) {  // pixtab (premul) + folded BN
    int g = t / 9, tap = t - (t / 9) * 9;
    int kh = tap / 3, kw = tap - kh * 3;
    int h = kh * 5 + g / 5, w = kw * 5 + (g - (g / 5) * 5);
    pixtab[t] = (h < 9 && w < 9) ? (unsigned short)((h * 9 + w) * PITCH)
                                 : (unsigned short)(ZROW * PITCH);
    float inv = gamma[t] * rsqrtf(var[t] + 1e-5f);
    bnf[t] = make_float2(inv, beta[t] - mean[t] * inv);
  }
  for (int t = tid; t < 2025; t += 1024) {  // w1 packed pairs (x-tap, k1-tap)
    int m = t / 9, q = t - m * 9;
    w1p[m * 12 + q] = pkh2(w1[m * 18 + q], w1[m * 18 + 9 + q]);
  }
  if (tid < 900) {                          // w2 packed o-pairs (o=0..7)
    int m = tid >> 2, j = tid & 3;
    w2p[m * 4 + j] = pkh2(w2[m * 9 + 2 * j], w2[m * 9 + 2 * j + 1]);
  }
  if (tid < 486) {                          // wk packed pairs + tails
    int m = tid / 6, j = tid - (tid / 6) * 6;
    const float* wr = wk + m * 9;
    unsigned int v;
    if (j < 4)       v = pkh2(wr[2 * j], wr[2 * j + 1]);
    else if (j == 4) v = pkh2(wr[8], 0.f);
    else             v = pkh2(0.f, wr[8]);
    wkpd[m * 6 + j] = v;
  }

  // hoisted phase-1b weights: chv fixed per thread -> registers
  const int chv = tid & 127;
  float wv_e[9], wv_o[9];
#pragma unroll
  for (int t = 0; t < 9; ++t) {
    wv_e[t] = wv[(2 * chv) * 9 + t];
    wv_o[t] = wv[(2 * chv + 1) * 9 + t];
  }
  const float bv_e = bv[2 * chv], bv_o = bv[2 * chv + 1];

  // ---- phase 0c: pack (f16) + LDS write (single drain of the x loads)
#pragma unroll
  for (int rep = 0; rep < 10; ++rep) xTd[adr[rep]] = pkh2(xe[rep], xo[rep]);
  if (tid < 128) xTd[adr[10]] = pkh2(xe[10], xo[10]);

  __syncthreads();

  // ---- phase 1a: k1[p][ch] = sum_j x[p][ch+j-4]*wk[p][j] + bk[p]
  // width-8 + row-cut. Call f: oct = f&31 (channel octet), pixel from f>>5.
  {
    auto k1fn8 = [&](int p, int oct) {
      const uint2* wrow2 = (const uint2*)(xTd + PITCHD * p + 4 * oct);
      uint2 r0 = wrow2[0], r1 = wrow2[1], r2 = wrow2[2], r3 = wrow2[3];
      unsigned int W[8] = {r0.x, r0.y, r1.x, r1.y, r2.x, r2.y, r3.x, r3.y};
      unsigned int A[7];
#pragma unroll
      for (int k2 = 0; k2 < 7; ++k2)
        A[k2] = (W[k2] >> 16) | (W[k2 + 1] << 16);
      const uint2* wkq = wkp + p * 3;
      uint2 wa = wkq[0], wb = wkq[1], wc = wkq[2];
      // wa.x=(w0,w1) wa.y=(w2,w3) wb.x=(w4,w5) wb.y=(w6,w7)
      // wc.x=(w8,0)  wc.y=(0,w8)
      float bkp = bk[p];
      float cc[8];
#pragma unroll
      for (int j2 = 0; j2 < 4; ++j2) {  // even ch j=2*j2, odd ch j=2*j2+1
        cc[2 * j2] =
            dot2(W[j2], wa.x, dot2(W[j2 + 1], wa.y, dot2(W[j2 + 2], wb.x,
            dot2(W[j2 + 3], wb.y, dot2(W[j2 + 4], wc.x, bkp)))));
        cc[2 * j2 + 1] =
            dot2(A[j2], wa.x, dot2(A[j2 + 1], wa.y, dot2(A[j2 + 2], wb.x,
            dot2(A[j2 + 3], wb.y, dot2(W[j2 + 4], wc.y, bkp)))));
      }
      unsigned int* dst = k1Td + PITCHD * p + 2 + 4 * oct;
      *(uint2*)dst = make_uint2(pkh2(cc[0], cc[1]), pkh2(cc[2], cc[3]));
      *(uint2*)(dst + 2) = make_uint2(pkh2(cc[4], cc[5]), pkh2(cc[6], cc[7]));
    };
    if (s == 0) {
      // rows 1..8 (72 pixels x 32 octets = 2304 calls)
#pragma unroll
      for (int rep = 0; rep < 2; ++rep) {
        int f = tid + rep * 1024;
        k1fn8(9 + (f >> 5), f & 31);
      }
      if (tid < 256) {
        int f = 2048 + tid;
        k1fn8(9 + (f >> 5), f & 31);
      }
    } else {
      // rows {0,1,4,5,6} (45 pixels x 32 octets = 1440 calls)
      auto prow = [&](int f) {
        int idx = f >> 5;
        int ri = idx / 9, col = idx - ri * 9;
        int row = ri + ((ri >= 2) ? 2 : 0);
        return row * 9 + col;
      };
      k1fn8(prow(tid), tid & 31);
      if (tid < 416) {
        int f = 1024 + tid;
        k1fn8(prow(f), f & 31);
      }
    }
  }

  // ---- phase 1b: v (3x3 depthwise) at the 18 pixels this half needs
  {
    auto vfn = [&](int f) {
      int e = __builtin_amdgcn_readfirstlane(f >> 7);  // 0..17 uniform
      int r0 = e / 6;
      int i = s * 3 + r0;  // v-pixel row 0..5
      int j = e - r0 * 6;  // v-pixel col 0..5
      float a_e = bv_e, a_o = bv_o;
#pragma unroll
      for (int di = 0; di < 3; ++di) {
        int ii = i + di - 1;
        if (ii < 0) continue;  // ii <= 6 < 9 always
#pragma unroll
        for (int dj = 0; dj < 3; ++dj) {
          int jj = j + dj - 1;
          if (jj < 0) continue;  // jj <= 6 < 9 always
          unsigned int d = xTd[PITCHD * (ii * 9 + jj) + 2 + chv];
          int t = di * 3 + dj;
          a_e = fmaf(lo_h(d), wv_e[t], a_e);
          a_o = fmaf(hi_h(d), wv_o[t], a_o);
        }
      }
      vTd[PITCHD * e + 2 + chv] = pkh2(a_e, a_o);
    };
#pragma unroll
    for (int rep = 0; rep < 2; ++rep) vfn(tid + rep * 1024);
    if (tid < 256) vfn(2048 + tid);
  }
  if (tid < 180) {  // vT channel-pad zeros
    int e = tid / 10, k2 = tid - (tid / 10) * 10;
    vT[e * PITCH + ((k2 < 4) ? k2 : (256 + k2))] = 0;
  }
  __syncthreads();

  // ---- phase 2: 15 deduped instances; 4 slots x 4 unrolled iterations
  const int s4 = tid >> 8;  // slot 0..3 (wave-uniform)
  const int ch = tid & 255;
  const int ci0 = ch / 9;
  const int tap0 = ch - ci0 * 9;
  float* outb = out + ((size_t)b * C + ch) * HW;

  // per-lane gather walk is instance-invariant
  int tq[9], cq[9];
  {
    int ci = ci0, tap = tap0;
#pragma unroll
    for (int q = 0; q < 9; ++q) {
      tq[q] = tap;
      cq[q] = 4 + ci;
      tap += 4;
      ci += 28;
      if (tap >= 9) { tap -= 9; ci += 1; }
    }
  }

#define PV_STORE(OH, OW)                                                   \
  do {                                                                     \
    int e_ = gh_i * 6 + ((OW)-3);                                          \
    const unsigned short* vrow_ = vT + e_ * PITCH;                         \
    float acc_ = 0.f;                                                      \
    _Pragma("unroll") for (int d_ = 0; d_ < 9; ++d_) acc_ =                \
        fmaf(a2[d_], us2f(vrow_[ch + d_]), acc_);                          \
    if ((OH) < 6 && (OW) < 6)                                              \
      acc_ = fmaf(acc_, inv_s,                                             \
                  us2f(k1T[(((OH) + 3) * 9 + ((OW) + 3)) * PITCH + 4 + ch])); \
    else                                                                   \
      acc_ *= inv_s;                                                       \
    if (valid_inst) outb[(OH)*9 + (OW)] = acc_;                            \
  } while (0)

#pragma unroll
  for (int k = 0; k < 4; ++k) {
    int idx = s4 * 4 + k;
    const bool valid_inst = (idx < 15);
    if (!valid_inst) idx = 14;  // dummy recomputes a real instance, no store
    int gh_i = idx / 5, gw_i = idx - (idx / 5) * 5;
    int oh = (s ? 6 : 3) + gh_i;
    int gh = s ? ((gh_i + 4) % 5) : (gh_i + 1);
    int g9 = __builtin_amdgcn_readfirstlane((gh * 5 + gw_i) * 9);

    // kq gather -> packed half2 (x_q, k1_q): 2 u16 reads + 1 lshl_or per q
    unsigned int kqp[9];
#pragma unroll
    for (int q = 0; q < 9; ++q) {
      int off = (int)pixtab[g9 + tq[q]] + cq[q];
      unsigned int xv = xT[off], kv = k1T[off];
      kqp[q] = xv | (kv << 16);
    }

    __builtin_amdgcn_s_setprio(1);
    // w1 (packed pairs, fdot2) -> folded BN -> ReLU
    float r[9];
#pragma unroll
    for (int o = 0; o < 9; ++o) {
      int m = g9 + o;
      const unsigned int* wp = w1p + m * 12;
      float a = 0.f;
#pragma unroll
      for (int q = 0; q < 9; ++q) a = dot2(kqp[q], wp[q], a);
      float2 bn = bnf[m];
      a = fmaf(a, bn.x, bn.y);
      r[o] = fmaxf(a, 0.f);
    }

    // w2 (packed o-pairs, fdot2) + b2 -> softmax (registers)
    unsigned int rp[4];
#pragma unroll
    for (int j = 0; j < 4; ++j) rp[j] = pkh2(r[2 * j], r[2 * j + 1]);
    float a2[9], mx = -1e30f;
#pragma unroll
    for (int d = 0; d < 9; ++d) {
      int m = g9 + d;
      const unsigned int* wq = w2p + m * 4;
      float a = b2[m];
#pragma unroll
      for (int j = 0; j < 4; ++j) a = dot2(rp[j], wq[j], a);
      a = fmaf(w2[m * 9 + 8], r[8], a);
      a2[d] = a;
      mx = fmaxf(mx, a);
    }
    const float L2E = 1.44269504f;
    float nmL = mx * -L2E;
    float ssum = 0.f;
#pragma unroll
    for (int d = 0; d < 9; ++d) {
      a2[d] = exp2_fast(fmaf(a2[d], L2E, nmL));
      ssum += a2[d];
    }
    float inv_s = __builtin_amdgcn_rcpf(ssum);
    __builtin_amdgcn_s_setprio(0);

    // PV + k1-add + store; gw==1 serves both ow=3 and ow=8
    int ow0 = (gw_i == 0) ? 7 : (gw_i + 2);
    PV_STORE(oh, ow0);
    if (gw_i == 1) PV_STORE(oh, 8);
  }
#undef PV_STORE

  // ---- epilogue: non-PV output pixels
  if (s == 0) {
    if (s4 < 3) {
      int oh = s4;  // rows 0..2: k1 where ow<6, else 0
#pragma unroll
      for (int ow = 0; ow < 9; ++ow) {
        float v2 = 0.f;
        if (ow < 6)
          v2 = us2f(k1T[((oh + 3) * 9 + (ow + 3)) * PITCH + 4 + ch]);
        outb[oh * 9 + ow] = v2;
      }
    } else {
      // rows 3..5, cols 0..2: k1-only
#pragma unroll
      for (int r0 = 0; r0 < 3; ++r0) {
        int oh = 3 + r0;
#pragma unroll
        for (int ow = 0; ow < 3; ++ow)
          outb[oh * 9 + ow] =
              us2f(k1T[((oh + 3) * 9 + (ow + 3)) * PITCH + 4 + ch]);
      }
    }
  } else if (s4 < 3) {
    int oh = 6 + s4;  // rows 6..8, cols 0..2: zero
    outb[oh * 9 + 0] = 0.f;
    outb[oh * 9 + 1] = 0.f;
    outb[oh * 9 + 2] = 0.f;
  }
}

extern "C" void kernel_launch(void* const* d_in, const int* in_sizes, int n_in,
                              void* d_out, int out_size, void* d_ws, size_t ws_size,
                              hipStream_t stream) {
  const float* x     = (const float*)d_in[0];
  const float* wk    = (const float*)d_in[1];
  const float* bk    = (const float*)d_in[2];
  const float* w1    = (const float*)d_in[3];
  const float* gamma = (const float*)d_in[4];
  const float* beta  = (const float*)d_in[5];
  const float* mean  = (const float*)d_in[6];
  const float* var   = (const float*)d_in[7];
  const float* w2    = (const float*)d_in[8];
  const float* b2    = (const float*)d_in[9];
  const float* wv    = (const float*)d_in[10];
  const float* bv    = (const float*)d_in[11];
  float* out = (float*)d_out;

  hipLaunchKernelGGL(semca_fused, dim3(256), dim3(1024), 0, stream,
                     x, wk, bk, w1, gamma, beta, mean, var, w2, b2, wv, bv, out);
}

// Round 15
// 24.664 us; speedup vs baseline: 1.1426x; 1.0244x over previous
//
#include <hip/hip_runtime.h>

#define C 256
#define HW 81
#define PITCH 292   // ushorts per pixel row: [4 pad][256 ch][32 pad] (even dword pitch)
#define PITCHD 146  // dwords per pixel row; 146%32=18 -> gather tap bases ~4-apart
#define ZROW 81     // zeroed row index for invalid gather taps

typedef __fp16 h2 __attribute__((ext_vector_type(2)));  // matches builtin V2h

__device__ __forceinline__ float us2f(unsigned short u) {  // f16 bits -> f32
  union { unsigned short s; __fp16 h; } c; c.s = u; return (float)c.h;
}
__device__ __forceinline__ float lo_h(unsigned int d) {
  union { unsigned int i; h2 h; } c; c.i = d; return (float)c.h.x;
}
__device__ __forceinline__ float hi_h(unsigned int d) {
  union { unsigned int i; h2 h; } c; c.i = d; return (float)c.h.y;
}
__device__ __forceinline__ unsigned int pkh2(float a, float b) {  // 1x cvt_pkrtz
  union { h2 h; unsigned int i; } c;
  c.h = __builtin_amdgcn_cvt_pkrtz(a, b);
  return c.i;
}
__device__ __forceinline__ h2 as_h2(unsigned int d) {
  union { unsigned int i; h2 h; } c; c.i = d; return c.h;
}
__device__ __forceinline__ unsigned int as_u32(h2 h) {
  union { h2 h; unsigned int i; } c; c.h = h; return c.i;
}
__device__ __forceinline__ float dot2(unsigned int a, unsigned int b, float c) {
#if __has_builtin(__builtin_amdgcn_fdot2)
  return __builtin_amdgcn_fdot2(as_h2(a), as_h2(b), c, false);
#else
  h2 x = as_h2(a), y = as_h2(b);
  return fmaf((float)x.y, (float)y.y, fmaf((float)x.x, (float)y.x, c));
#endif
}
__device__ __forceinline__ float exp2_fast(float x) {
#if __has_builtin(__builtin_amdgcn_exp2f)
  return __builtin_amdgcn_exp2f(x);
#else
  return __expf(x * 0.6931471805599453f);
#endif
}

// ---------------------------------------------------------------------------
// Fully fused SeMCA. Block = (b, s): s=0 -> output rows 3..5 (+epilogue rows
// 3..5 cols 0..2), s=1 -> rows 6..8 AND rows 0..2 (+zeros 6..8 cols 0..2).
// 1024 threads = 4 instance-slots x 256 channels. 2 barriers.
// R15 = R14 base (25.27us) + two issue-diet cuts:
//  - symmetric k1 row-split (54/54): epilogue rows 0..2 (k1 rows 3..5) move
//    from s=0 to s=1. s=0 computes k1 rows {1,2,3,6,7,8} only (rows 4,5
//    provably unread by s=0); s=1 computes {0,1,3,4,5,6} (gather {0,1,4,5,6}
//    + epilogue {3,4,5}). Critical s=0 block: 1a 2.25 -> 1.69 calls/thread,
//    -9 stores on its 12 s4<3 waves.
//  - phase 1b in packed f16: xT dwords are (even,odd) f16 pairs already;
//    acc = v_pk_fma_f16(d, wvp[t], acc) halves the tap FMAs and kills the
//    final pack (f16 accum of 9 small products, ~1e-3 error, safe).
// Everything else byte-identical to R14.
// ---------------------------------------------------------------------------
__global__ __launch_bounds__(1024) void semca_fused(
    const float* __restrict__ x, const float* __restrict__ wk,
    const float* __restrict__ bk, const float* __restrict__ w1,
    const float* __restrict__ gamma, const float* __restrict__ beta,
    const float* __restrict__ mean, const float* __restrict__ var,
    const float* __restrict__ w2, const float* __restrict__ b2,
    const float* __restrict__ wv, const float* __restrict__ bv,
    float* __restrict__ out) {
  __shared__ unsigned short xT[82 * PITCH];   // 47,888 B (row 81 = zeros), f16
  __shared__ unsigned short k1T[82 * PITCH];  // 47,888 B (row 81 = zeros), f16
  __shared__ unsigned short vT[18 * PITCH];   // 10,512 B, f16
  __shared__ unsigned short pixtab[228];      //    456 B (premultiplied by PITCH)
  __shared__ float2 bnf[225];                 //  1,800 B
  __shared__ unsigned int w1p[225 * 12];      // 10,800 B half2 pairs, 48B/row
  __shared__ unsigned int w2p[225 * 4];       //  3,600 B half2 o-pairs (16B/row)
  __shared__ uint2 wkp[81 * 3];               //  1,944 B wk half2: 6 dwords/pixel

  const int blk = blockIdx.x;
  const int b = (blk & 7) * 16 + ((blk >> 3) & 15);  // XCD-paired, bijective
  const int s = blk >> 7;
  const int tid = threadIdx.x;
  const float* xb = x + (size_t)b * (C * HW);

  unsigned int* xTd = (unsigned int*)xT;
  unsigned int* k1Td = (unsigned int*)k1T;
  unsigned int* vTd = (unsigned int*)vT;
  unsigned int* wkpd = (unsigned int*)wkp;

  // ---- phase 0a: issue ALL x loads first (registers), incremental walk
  float xe[11], xo[11];
  int adr[11];
  {
    int chp = tid / HW;            // single division
    int p = tid - chp * HW;
#pragma unroll
    for (int rep = 0; rep < 10; ++rep) {
      const float* base = xb + (2 * chp) * HW + p;
      xe[rep] = base[0];
      xo[rep] = base[HW];
      adr[rep] = PITCHD * p + 2 + chp;
      chp += 12;                   // advance f by 1024 = 12*81 + 52
      p += 52;
      if (p >= HW) { p -= HW; chp += 1; }
    }
    if (tid < 128) {               // tail item f = 10240 + tid
      int f = 10240 + tid;
      int c2 = f / HW, p2 = f - c2 * HW;
      xe[10] = xb[2 * c2 * HW + p2];
      xo[10] = xb[(2 * c2 + 1) * HW + p2];
      adr[10] = PITCHD * p2 + 2 + c2;
    }
  }

  // ---- phase 0b: independent work under the load shadow
  for (int t = tid; t < 810; t += 1024) {  // x channel-pad zeros
    int p = t / 10, k2 = t - (t / 10) * 10;
    xT[p * PITCH + ((k2 < 4) ? k2 : (256 + k2))] = 0;
  }
  if (tid < PITCHD) {                      // zero row 81 of xT and k1T
    xTd[PITCHD * ZROW + tid] = 0;
    k1Td[PITCHD * ZROW + tid] = 0;
  }
  for (int t = tid; t < 225; t += 1024) {  // pixtab (premul) + folded BN
    int g = t / 9, tap = t - (t / 9) * 9;
    int kh = tap / 3, kw = tap - kh * 3;
    int h = kh * 5 + g / 5, w = kw * 5 + (g - (g / 5) * 5);
    pixtab[t] = (h < 9 && w < 9) ? (unsigned short)((h * 9 + w) * PITCH)
                                 : (unsigned short)(ZROW * PITCH);
    float inv = gamma[t] * rsqrtf(var[t] + 1e-5f);
    bnf[t] = make_float2(inv, beta[t] - mean[t] * inv);
  }
  for (int t = tid; t < 2025; t += 1024) {  // w1 packed pairs (x-tap, k1-tap)
    int m = t / 9, q = t - m * 9;
    w1p[m * 12 + q] = pkh2(w1[m * 18 + q], w1[m * 18 + 9 + q]);
  }
  if (tid < 900) {                          // w2 packed o-pairs (o=0..7)
    int m = tid >> 2, j = tid & 3;
    w2p[m * 4 + j] = pkh2(w2[m * 9 + 2 * j], w2[m * 9 + 2 * j + 1]);
  }
  if (tid < 486) {                          // wk packed pairs + tails
    int m = tid / 6, j = tid - (tid / 6) * 6;
    const float* wr = wk + m * 9;
    unsigned int v;
    if (j < 4)       v = pkh2(wr[2 * j], wr[2 * j + 1]);
    else if (j == 4) v = pkh2(wr[8], 0.f);
    else             v = pkh2(0.f, wr[8]);
    wkpd[m * 6 + j] = v;
  }

  // hoisted phase-1b weights: chv fixed per thread -> packed h2 registers
  const int chv = tid & 127;
  unsigned int wvp[9];
#pragma unroll
  for (int t = 0; t < 9; ++t)
    wvp[t] = pkh2(wv[(2 * chv) * 9 + t], wv[(2 * chv + 1) * 9 + t]);
  const unsigned int bvp = pkh2(bv[2 * chv], bv[2 * chv + 1]);

  // ---- phase 0c: pack (f16) + LDS write (single drain of the x loads)
#pragma unroll
  for (int rep = 0; rep < 10; ++rep) xTd[adr[rep]] = pkh2(xe[rep], xo[rep]);
  if (tid < 128) xTd[adr[10]] = pkh2(xe[10], xo[10]);

  __syncthreads();

  // ---- phase 1a: k1[p][ch] = sum_j x[p][ch+j-4]*wk[p][j] + bk[p]
  // width-8 + symmetric row-cut: 54 rows x 32 octets = 1728 calls per half.
  {
    auto k1fn8 = [&](int p, int oct) {
      const uint2* wrow2 = (const uint2*)(xTd + PITCHD * p + 4 * oct);
      uint2 r0 = wrow2[0], r1 = wrow2[1], r2 = wrow2[2], r3 = wrow2[3];
      unsigned int W[8] = {r0.x, r0.y, r1.x, r1.y, r2.x, r2.y, r3.x, r3.y};
      unsigned int A[7];
#pragma unroll
      for (int k2 = 0; k2 < 7; ++k2)
        A[k2] = (W[k2] >> 16) | (W[k2 + 1] << 16);
      const uint2* wkq = wkp + p * 3;
      uint2 wa = wkq[0], wb = wkq[1], wc = wkq[2];
      // wa.x=(w0,w1) wa.y=(w2,w3) wb.x=(w4,w5) wb.y=(w6,w7)
      // wc.x=(w8,0)  wc.y=(0,w8)
      float bkp = bk[p];
      float cc[8];
#pragma unroll
      for (int j2 = 0; j2 < 4; ++j2) {  // even ch j=2*j2, odd ch j=2*j2+1
        cc[2 * j2] =
            dot2(W[j2], wa.x, dot2(W[j2 + 1], wa.y, dot2(W[j2 + 2], wb.x,
            dot2(W[j2 + 3], wb.y, dot2(W[j2 + 4], wc.x, bkp)))));
        cc[2 * j2 + 1] =
            dot2(A[j2], wa.x, dot2(A[j2 + 1], wa.y, dot2(A[j2 + 2], wb.x,
            dot2(A[j2 + 3], wb.y, dot2(W[j2 + 4], wc.y, bkp)))));
      }
      unsigned int* dst = k1Td + PITCHD * p + 2 + 4 * oct;
      *(uint2*)dst = make_uint2(pkh2(cc[0], cc[1]), pkh2(cc[2], cc[3]));
      *(uint2*)(dst + 2) = make_uint2(pkh2(cc[4], cc[5]), pkh2(cc[6], cc[7]));
    };
    // s=0 rows {1,2,3,6,7,8}; s=1 rows {0,1,3,4,5,6} (uniform branch)
    auto prow = [&](int f) {
      int idx = f >> 5;
      int ri = idx / 9, col = idx - ri * 9;
      int row = s == 0 ? (ri + ((ri < 3) ? 1 : 3)) : (ri + ((ri >= 2) ? 1 : 0));
      return row * 9 + col;
    };
    k1fn8(prow(tid), tid & 31);
    if (tid < 704) {
      int f = 1024 + tid;
      k1fn8(prow(f), f & 31);
    }
  }

  // ---- phase 1b: v (3x3 depthwise), packed-f16 math (pk_fma), 18 pixels
  {
    auto vfn = [&](int f) {
      int e = __builtin_amdgcn_readfirstlane(f >> 7);  // 0..17 uniform
      int r0 = e / 6;
      int i = s * 3 + r0;  // v-pixel row 0..5
      int j = e - r0 * 6;  // v-pixel col 0..5
      h2 acc = as_h2(bvp);
#pragma unroll
      for (int di = 0; di < 3; ++di) {
        int ii = i + di - 1;
        if (ii < 0) continue;  // ii <= 6 < 9 always
#pragma unroll
        for (int dj = 0; dj < 3; ++dj) {
          int jj = j + dj - 1;
          if (jj < 0) continue;  // jj <= 6 < 9 always
          unsigned int d = xTd[PITCHD * (ii * 9 + jj) + 2 + chv];
          int t = di * 3 + dj;
          acc = as_h2(d) * as_h2(wvp[t]) + acc;  // v_pk_fma_f16
        }
      }
      vTd[PITCHD * e + 2 + chv] = as_u32(acc);
    };
#pragma unroll
    for (int rep = 0; rep < 2; ++rep) vfn(tid + rep * 1024);
    if (tid < 256) vfn(2048 + tid);
  }
  if (tid < 180) {  // vT channel-pad zeros
    int e = tid / 10, k2 = tid - (tid / 10) * 10;
    vT[e * PITCH + ((k2 < 4) ? k2 : (256 + k2))] = 0;
  }
  __syncthreads();

  // ---- phase 2: 15 deduped instances; 4 slots x 4 unrolled iterations
  const int s4 = tid >> 8;  // slot 0..3 (wave-uniform)
  const int ch = tid & 255;
  const int ci0 = ch / 9;
  const int tap0 = ch - ci0 * 9;
  float* outb = out + ((size_t)b * C + ch) * HW;

  // per-lane gather walk is instance-invariant
  int tq[9], cq[9];
  {
    int ci = ci0, tap = tap0;
#pragma unroll
    for (int q = 0; q < 9; ++q) {
      tq[q] = tap;
      cq[q] = 4 + ci;
      tap += 4;
      ci += 28;
      if (tap >= 9) { tap -= 9; ci += 1; }
    }
  }

#define PV_STORE(OH, OW)                                                   \
  do {                                                                     \
    int e_ = gh_i * 6 + ((OW)-3);                                          \
    const unsigned short* vrow_ = vT + e_ * PITCH;                         \
    float acc_ = 0.f;                                                      \
    _Pragma("unroll") for (int d_ = 0; d_ < 9; ++d_) acc_ =                \
        fmaf(a2[d_], us2f(vrow_[ch + d_]), acc_);                          \
    if ((OH) < 6 && (OW) < 6)                                              \
      acc_ = fmaf(acc_, inv_s,                                             \
                  us2f(k1T[(((OH) + 3) * 9 + ((OW) + 3)) * PITCH + 4 + ch])); \
    else                                                                   \
      acc_ *= inv_s;                                                       \
    if (valid_inst) outb[(OH)*9 + (OW)] = acc_;                            \
  } while (0)

#pragma unroll
  for (int k = 0; k < 4; ++k) {
    int idx = s4 * 4 + k;
    const bool valid_inst = (idx < 15);
    if (!valid_inst) idx = 14;  // dummy recomputes a real instance, no store
    int gh_i = idx / 5, gw_i = idx - (idx / 5) * 5;
    int oh = (s ? 6 : 3) + gh_i;
    int gh = s ? ((gh_i + 4) % 5) : (gh_i + 1);
    int g9 = __builtin_amdgcn_readfirstlane((gh * 5 + gw_i) * 9);

    // kq gather -> packed half2 (x_q, k1_q): 2 u16 reads + 1 lshl_or per q
    unsigned int kqp[9];
#pragma unroll
    for (int q = 0; q < 9; ++q) {
      int off = (int)pixtab[g9 + tq[q]] + cq[q];
      unsigned int xv = xT[off], kv = k1T[off];
      kqp[q] = xv | (kv << 16);
    }

    __builtin_amdgcn_s_setprio(1);
    // w1 (packed pairs, fdot2) -> folded BN -> ReLU
    float r[9];
#pragma unroll
    for (int o = 0; o < 9; ++o) {
      int m = g9 + o;
      const unsigned int* wp = w1p + m * 12;
      float a = 0.f;
#pragma unroll
      for (int q = 0; q < 9; ++q) a = dot2(kqp[q], wp[q], a);
      float2 bn = bnf[m];
      a = fmaf(a, bn.x, bn.y);
      r[o] = fmaxf(a, 0.f);
    }

    // w2 (packed o-pairs, fdot2) + b2 -> softmax (registers)
    unsigned int rp[4];
#pragma unroll
    for (int j = 0; j < 4; ++j) rp[j] = pkh2(r[2 * j], r[2 * j + 1]);
    float a2[9], mx = -1e30f;
#pragma unroll
    for (int d = 0; d < 9; ++d) {
      int m = g9 + d;
      const unsigned int* wq = w2p + m * 4;
      float a = b2[m];
#pragma unroll
      for (int j = 0; j < 4; ++j) a = dot2(rp[j], wq[j], a);
      a = fmaf(w2[m * 9 + 8], r[8], a);
      a2[d] = a;
      mx = fmaxf(mx, a);
    }
    const float L2E = 1.44269504f;
    float nmL = mx * -L2E;
    float ssum = 0.f;
#pragma unroll
    for (int d = 0; d < 9; ++d) {
      a2[d] = exp2_fast(fmaf(a2[d], L2E, nmL));
      ssum += a2[d];
    }
    float inv_s = __builtin_amdgcn_rcpf(ssum);
    __builtin_amdgcn_s_setprio(0);

    // PV + k1-add + store; gw==1 serves both ow=3 and ow=8
    int ow0 = (gw_i == 0) ? 7 : (gw_i + 2);
    PV_STORE(oh, ow0);
    if (gw_i == 1) PV_STORE(oh, 8);
  }
#undef PV_STORE

  // ---- epilogue: non-PV output pixels (rebalanced: rows 0..2 now on s=1)
  if (s == 0) {
    if (s4 == 3) {
      // rows 3..5, cols 0..2: k1-only
#pragma unroll
      for (int r0 = 0; r0 < 3; ++r0) {
        int oh = 3 + r0;
#pragma unroll
        for (int ow = 0; ow < 3; ++ow)
          outb[oh * 9 + ow] =
              us2f(k1T[((oh + 3) * 9 + (ow + 3)) * PITCH + 4 + ch]);
      }
    }
  } else {
    if (s4 < 3) {
      int oh = s4;  // rows 0..2: k1 where ow<6, else 0
#pragma unroll
      for (int ow = 0; ow < 9; ++ow) {
        float v2 = 0.f;
        if (ow < 6)
          v2 = us2f(k1T[((oh + 3) * 9 + (ow + 3)) * PITCH + 4 + ch]);
        outb[oh * 9 + ow] = v2;
      }
    } else {
      // rows 6..8, cols 0..2: zero
#pragma unroll
      for (int r0 = 0; r0 < 3; ++r0) {
        int oh = 6 + r0;
        outb[oh * 9 + 0] = 0.f;
        outb[oh * 9 + 1] = 0.f;
        outb[oh * 9 + 2] = 0.f;
      }
    }
  }
}

extern "C" void kernel_launch(void* const* d_in, const int* in_sizes, int n_in,
                              void* d_out, int out_size, void* d_ws, size_t ws_size,
                              hipStream_t stream) {
  const float* x     = (const float*)d_in[0];
  const float* wk    = (const float*)d_in[1];
  const float* bk    = (const float*)d_in[2];
  const float* w1    = (const float*)d_in[3];
  const float* gamma = (const float*)d_in[4];
  const float* beta  = (const float*)d_in[5];
  const float* mean  = (const float*)d_in[6];
  const float* var   = (const float*)d_in[7];
  const float* w2    = (const float*)d_in[8];
  const float* b2    = (const float*)d_in[9];
  const float* wv    = (const float*)d_in[10];
  const float* bv    = (const float*)d_in[11];
  float* out = (float*)d_out;

  hipLaunchKernelGGL(semca_fused, dim3(256), dim3(1024), 0, stream,
                     x, wk, bk, w1, gamma, beta, mean, var, w2, b2, wv, bv, out);
}

// Round 16
// 24.395 us; speedup vs baseline: 1.1552x; 1.0110x over previous
//
#include <hip/hip_runtime.h>

#define C 256
#define HW 81
#define PITCH 292   // ushorts per pixel row: [4 pad][256 ch][32 pad] (even dword pitch)
#define PITCHD 146  // dwords per pixel row; 146%32=18 -> gather tap bases ~4-apart
#define ZROW 81     // zeroed row index for invalid gather taps

typedef __fp16 h2 __attribute__((ext_vector_type(2)));  // matches builtin V2h

__device__ __forceinline__ float us2f(unsigned short u) {  // f16 bits -> f32
  union { unsigned short s; __fp16 h; } c; c.s = u; return (float)c.h;
}
__device__ __forceinline__ float lo_h(unsigned int d) {
  union { unsigned int i; h2 h; } c; c.i = d; return (float)c.h.x;
}
__device__ __forceinline__ float hi_h(unsigned int d) {
  union { unsigned int i; h2 h; } c; c.i = d; return (float)c.h.y;
}
__device__ __forceinline__ unsigned int pkh2(float a, float b) {  // 1x cvt_pkrtz
  union { h2 h; unsigned int i; } c;
  c.h = __builtin_amdgcn_cvt_pkrtz(a, b);
  return c.i;
}
__device__ __forceinline__ h2 as_h2(unsigned int d) {
  union { unsigned int i; h2 h; } c; c.i = d; return c.h;
}
__device__ __forceinline__ unsigned int as_u32(h2 h) {
  union { h2 h; unsigned int i; } c; c.h = h; return c.i;
}
__device__ __forceinline__ float dot2(unsigned int a, unsigned int b, float c) {
#if __has_builtin(__builtin_amdgcn_fdot2)
  return __builtin_amdgcn_fdot2(as_h2(a), as_h2(b), c, false);
#else
  h2 x = as_h2(a), y = as_h2(b);
  return fmaf((float)x.y, (float)y.y, fmaf((float)x.x, (float)y.x, c));
#endif
}
__device__ __forceinline__ float exp2_fast(float x) {
#if __has_builtin(__builtin_amdgcn_exp2f)
  return __builtin_amdgcn_exp2f(x);
#else
  return __expf(x * 0.6931471805599453f);
#endif
}

// ---------------------------------------------------------------------------
// Fully fused SeMCA. Block = (b, s): s=0 -> output rows 3..5 (+epilogue rows
// 3..5 cols 0..2), s=1 -> rows 6..8 AND rows 0..2 (+zeros 6..8 cols 0..2).
// 1024 threads = 4 instance-slots x 256 channels. 2 barriers.
// R16 = R15 base (24.66us) + two issue-diet cuts:
//  - BN folded into w1p: weights pre-scaled by inv_m at build (under load
//    shadow); dot chain seeded with shift[m]. Phase 2 loses 9 fmaf + the
//    float2 bnf reads per instance (~70 instr/thread).
//  - dummy instance eliminated: 15 instances as 4/4/4/3; slot-3 waves skip
//    k=3 (uniform branch, one wave per SIMD frees issue slots); stores are
//    now unconditional (valid_inst mask dropped).
// Everything else byte-identical to R15.
// ---------------------------------------------------------------------------
__global__ __launch_bounds__(1024) void semca_fused(
    const float* __restrict__ x, const float* __restrict__ wk,
    const float* __restrict__ bk, const float* __restrict__ w1,
    const float* __restrict__ gamma, const float* __restrict__ beta,
    const float* __restrict__ mean, const float* __restrict__ var,
    const float* __restrict__ w2, const float* __restrict__ b2,
    const float* __restrict__ wv, const float* __restrict__ bv,
    float* __restrict__ out) {
  __shared__ unsigned short xT[82 * PITCH];   // 47,888 B (row 81 = zeros), f16
  __shared__ unsigned short k1T[82 * PITCH];  // 47,888 B (row 81 = zeros), f16
  __shared__ unsigned short vT[18 * PITCH];   // 10,512 B, f16
  __shared__ unsigned short pixtab[228];      //    456 B (premultiplied by PITCH)
  __shared__ float bnf1[225];                 //    900 B (BN shift only)
  __shared__ unsigned int w1p[225 * 12];      // 10,800 B half2 pairs, BN-scaled
  __shared__ unsigned int w2p[225 * 4];       //  3,600 B half2 o-pairs (16B/row)
  __shared__ uint2 wkp[81 * 3];               //  1,944 B wk half2: 6 dwords/pixel

  const int blk = blockIdx.x;
  const int b = (blk & 7) * 16 + ((blk >> 3) & 15);  // XCD-paired, bijective
  const int s = blk >> 7;
  const int tid = threadIdx.x;
  const float* xb = x + (size_t)b * (C * HW);

  unsigned int* xTd = (unsigned int*)xT;
  unsigned int* k1Td = (unsigned int*)k1T;
  unsigned int* vTd = (unsigned int*)vT;
  unsigned int* wkpd = (unsigned int*)wkp;

  // ---- phase 0a: issue ALL x loads first (registers), incremental walk
  float xe[11], xo[11];
  int adr[11];
  {
    int chp = tid / HW;            // single division
    int p = tid - chp * HW;
#pragma unroll
    for (int rep = 0; rep < 10; ++rep) {
      const float* base = xb + (2 * chp) * HW + p;
      xe[rep] = base[0];
      xo[rep] = base[HW];
      adr[rep] = PITCHD * p + 2 + chp;
      chp += 12;                   // advance f by 1024 = 12*81 + 52
      p += 52;
      if (p >= HW) { p -= HW; chp += 1; }
    }
    if (tid < 128) {               // tail item f = 10240 + tid
      int f = 10240 + tid;
      int c2 = f / HW, p2 = f - c2 * HW;
      xe[10] = xb[2 * c2 * HW + p2];
      xo[10] = xb[(2 * c2 + 1) * HW + p2];
      adr[10] = PITCHD * p2 + 2 + c2;
    }
  }

  // ---- phase 0b: independent work under the load shadow
  for (int t = tid; t < 810; t += 1024) {  // x channel-pad zeros
    int p = t / 10, k2 = t - (t / 10) * 10;
    xT[p * PITCH + ((k2 < 4) ? k2 : (256 + k2))] = 0;
  }
  if (tid < PITCHD) {                      // zero row 81 of xT and k1T
    xTd[PITCHD * ZROW + tid] = 0;
    k1Td[PITCHD * ZROW + tid] = 0;
  }
  for (int t = tid; t < 225; t += 1024) {  // pixtab (premul) + BN shift
    int g = t / 9, tap = t - (t / 9) * 9;
    int kh = tap / 3, kw = tap - kh * 3;
    int h = kh * 5 + g / 5, w = kw * 5 + (g - (g / 5) * 5);
    pixtab[t] = (h < 9 && w < 9) ? (unsigned short)((h * 9 + w) * PITCH)
                                 : (unsigned short)(ZROW * PITCH);
    float inv = gamma[t] * rsqrtf(var[t] + 1e-5f);
    bnf1[t] = beta[t] - mean[t] * inv;
  }
  for (int t = tid; t < 2025; t += 1024) {  // w1 packed pairs, BN-scaled
    int m = t / 9, q = t - m * 9;
    float inv = gamma[m] * rsqrtf(var[m] + 1e-5f);
    w1p[m * 12 + q] = pkh2(w1[m * 18 + q] * inv, w1[m * 18 + 9 + q] * inv);
  }
  if (tid < 900) {                          // w2 packed o-pairs (o=0..7)
    int m = tid >> 2, j = tid & 3;
    w2p[m * 4 + j] = pkh2(w2[m * 9 + 2 * j], w2[m * 9 + 2 * j + 1]);
  }
  if (tid < 486) {                          // wk packed pairs + tails
    int m = tid / 6, j = tid - (tid / 6) * 6;
    const float* wr = wk + m * 9;
    unsigned int v;
    if (j < 4)       v = pkh2(wr[2 * j], wr[2 * j + 1]);
    else if (j == 4) v = pkh2(wr[8], 0.f);
    else             v = pkh2(0.f, wr[8]);
    wkpd[m * 6 + j] = v;
  }

  // hoisted phase-1b weights: chv fixed per thread -> packed h2 registers
  const int chv = tid & 127;
  unsigned int wvp[9];
#pragma unroll
  for (int t = 0; t < 9; ++t)
    wvp[t] = pkh2(wv[(2 * chv) * 9 + t], wv[(2 * chv + 1) * 9 + t]);
  const unsigned int bvp = pkh2(bv[2 * chv], bv[2 * chv + 1]);

  // ---- phase 0c: pack (f16) + LDS write (single drain of the x loads)
#pragma unroll
  for (int rep = 0; rep < 10; ++rep) xTd[adr[rep]] = pkh2(xe[rep], xo[rep]);
  if (tid < 128) xTd[adr[10]] = pkh2(xe[10], xo[10]);

  __syncthreads();

  // ---- phase 1a: k1[p][ch] = sum_j x[p][ch+j-4]*wk[p][j] + bk[p]
  // width-8 + symmetric row-cut: 54 rows x 32 octets = 1728 calls per half.
  {
    auto k1fn8 = [&](int p, int oct) {
      const uint2* wrow2 = (const uint2*)(xTd + PITCHD * p + 4 * oct);
      uint2 r0 = wrow2[0], r1 = wrow2[1], r2 = wrow2[2], r3 = wrow2[3];
      unsigned int W[8] = {r0.x, r0.y, r1.x, r1.y, r2.x, r2.y, r3.x, r3.y};
      unsigned int A[7];
#pragma unroll
      for (int k2 = 0; k2 < 7; ++k2)
        A[k2] = (W[k2] >> 16) | (W[k2 + 1] << 16);
      const uint2* wkq = wkp + p * 3;
      uint2 wa = wkq[0], wb = wkq[1], wc = wkq[2];
      // wa.x=(w0,w1) wa.y=(w2,w3) wb.x=(w4,w5) wb.y=(w6,w7)
      // wc.x=(w8,0)  wc.y=(0,w8)
      float bkp = bk[p];
      float cc[8];
#pragma unroll
      for (int j2 = 0; j2 < 4; ++j2) {  // even ch j=2*j2, odd ch j=2*j2+1
        cc[2 * j2] =
            dot2(W[j2], wa.x, dot2(W[j2 + 1], wa.y, dot2(W[j2 + 2], wb.x,
            dot2(W[j2 + 3], wb.y, dot2(W[j2 + 4], wc.x, bkp)))));
        cc[2 * j2 + 1] =
            dot2(A[j2], wa.x, dot2(A[j2 + 1], wa.y, dot2(A[j2 + 2], wb.x,
            dot2(A[j2 + 3], wb.y, dot2(W[j2 + 4], wc.y, bkp)))));
      }
      unsigned int* dst = k1Td + PITCHD * p + 2 + 4 * oct;
      *(uint2*)dst = make_uint2(pkh2(cc[0], cc[1]), pkh2(cc[2], cc[3]));
      *(uint2*)(dst + 2) = make_uint2(pkh2(cc[4], cc[5]), pkh2(cc[6], cc[7]));
    };
    // s=0 rows {1,2,3,6,7,8}; s=1 rows {0,1,3,4,5,6} (uniform branch)
    auto prow = [&](int f) {
      int idx = f >> 5;
      int ri = idx / 9, col = idx - ri * 9;
      int row = s == 0 ? (ri + ((ri < 3) ? 1 : 3)) : (ri + ((ri >= 2) ? 1 : 0));
      return row * 9 + col;
    };
    k1fn8(prow(tid), tid & 31);
    if (tid < 704) {
      int f = 1024 + tid;
      k1fn8(prow(f), f & 31);
    }
  }

  // ---- phase 1b: v (3x3 depthwise), packed-f16 math (pk_fma), 18 pixels
  {
    auto vfn = [&](int f) {
      int e = __builtin_amdgcn_readfirstlane(f >> 7);  // 0..17 uniform
      int r0 = e / 6;
      int i = s * 3 + r0;  // v-pixel row 0..5
      int j = e - r0 * 6;  // v-pixel col 0..5
      h2 acc = as_h2(bvp);
#pragma unroll
      for (int di = 0; di < 3; ++di) {
        int ii = i + di - 1;
        if (ii < 0) continue;  // ii <= 6 < 9 always
#pragma unroll
        for (int dj = 0; dj < 3; ++dj) {
          int jj = j + dj - 1;
          if (jj < 0) continue;  // jj <= 6 < 9 always
          unsigned int d = xTd[PITCHD * (ii * 9 + jj) + 2 + chv];
          int t = di * 3 + dj;
          acc = as_h2(d) * as_h2(wvp[t]) + acc;  // v_pk_fma_f16
        }
      }
      vTd[PITCHD * e + 2 + chv] = as_u32(acc);
    };
#pragma unroll
    for (int rep = 0; rep < 2; ++rep) vfn(tid + rep * 1024);
    if (tid < 256) vfn(2048 + tid);
  }
  if (tid < 180) {  // vT channel-pad zeros
    int e = tid / 10, k2 = tid - (tid / 10) * 10;
    vT[e * PITCH + ((k2 < 4) ? k2 : (256 + k2))] = 0;
  }
  __syncthreads();

  // ---- phase 2: 15 instances as 4/4/4/3 (slot 3 skips k=3; no dummy)
  const int s4 = tid >> 8;  // slot 0..3 (wave-uniform)
  const int ch = tid & 255;
  const int ci0 = ch / 9;
  const int tap0 = ch - ci0 * 9;
  float* outb = out + ((size_t)b * C + ch) * HW;

  // per-lane gather walk is instance-invariant
  int tq[9], cq[9];
  {
    int ci = ci0, tap = tap0;
#pragma unroll
    for (int q = 0; q < 9; ++q) {
      tq[q] = tap;
      cq[q] = 4 + ci;
      tap += 4;
      ci += 28;
      if (tap >= 9) { tap -= 9; ci += 1; }
    }
  }

#define PV_STORE(OH, OW)                                                   \
  do {                                                                     \
    int e_ = gh_i * 6 + ((OW)-3);                                          \
    const unsigned short* vrow_ = vT + e_ * PITCH;                         \
    float acc_ = 0.f;                                                      \
    _Pragma("unroll") for (int d_ = 0; d_ < 9; ++d_) acc_ =                \
        fmaf(a2[d_], us2f(vrow_[ch + d_]), acc_);                          \
    if ((OH) < 6 && (OW) < 6)                                              \
      acc_ = fmaf(acc_, inv_s,                                             \
                  us2f(k1T[(((OH) + 3) * 9 + ((OW) + 3)) * PITCH + 4 + ch])); \
    else                                                                   \
      acc_ *= inv_s;                                                       \
    outb[(OH)*9 + (OW)] = acc_;                                            \
  } while (0)

#pragma unroll
  for (int k = 0; k < 4; ++k) {
    if (s4 == 3 && k == 3) break;  // slot 3: 3 real instances, no dummy
    int idx = s4 * 4 + k;          // 0..14, always valid
    int gh_i = idx / 5, gw_i = idx - (idx / 5) * 5;
    int oh = (s ? 6 : 3) + gh_i;
    int gh = s ? ((gh_i + 4) % 5) : (gh_i + 1);
    int g9 = __builtin_amdgcn_readfirstlane((gh * 5 + gw_i) * 9);

    // kq gather -> packed half2 (x_q, k1_q): 2 u16 reads + 1 lshl_or per q
    unsigned int kqp[9];
#pragma unroll
    for (int q = 0; q < 9; ++q) {
      int off = (int)pixtab[g9 + tq[q]] + cq[q];
      unsigned int xv = xT[off], kv = k1T[off];
      kqp[q] = xv | (kv << 16);
    }

    __builtin_amdgcn_s_setprio(1);
    // w1 (BN-scaled pairs, fdot2, seeded with BN shift) -> ReLU
    float r[9];
#pragma unroll
    for (int o = 0; o < 9; ++o) {
      int m = g9 + o;
      const unsigned int* wp = w1p + m * 12;
      float a = bnf1[m];
#pragma unroll
      for (int q = 0; q < 9; ++q) a = dot2(kqp[q], wp[q], a);
      r[o] = fmaxf(a, 0.f);
    }

    // w2 (packed o-pairs, fdot2) + b2 -> softmax (registers)
    unsigned int rp[4];
#pragma unroll
    for (int j = 0; j < 4; ++j) rp[j] = pkh2(r[2 * j], r[2 * j + 1]);
    float a2[9], mx = -1e30f;
#pragma unroll
    for (int d = 0; d < 9; ++d) {
      int m = g9 + d;
      const unsigned int* wq = w2p + m * 4;
      float a = b2[m];
#pragma unroll
      for (int j = 0; j < 4; ++j) a = dot2(rp[j], wq[j], a);
      a = fmaf(w2[m * 9 + 8], r[8], a);
      a2[d] = a;
      mx = fmaxf(mx, a);
    }
    const float L2E = 1.44269504f;
    float nmL = mx * -L2E;
    float ssum = 0.f;
#pragma unroll
    for (int d = 0; d < 9; ++d) {
      a2[d] = exp2_fast(fmaf(a2[d], L2E, nmL));
      ssum += a2[d];
    }
    float inv_s = __builtin_amdgcn_rcpf(ssum);
    __builtin_amdgcn_s_setprio(0);

    // PV + k1-add + store; gw==1 serves both ow=3 and ow=8
    int ow0 = (gw_i == 0) ? 7 : (gw_i + 2);
    PV_STORE(oh, ow0);
    if (gw_i == 1) PV_STORE(oh, 8);
  }
#undef PV_STORE

  // ---- epilogue: non-PV output pixels (rebalanced: rows 0..2 on s=1)
  if (s == 0) {
    if (s4 == 3) {
      // rows 3..5, cols 0..2: k1-only
#pragma unroll
      for (int r0 = 0; r0 < 3; ++r0) {
        int oh = 3 + r0;
#pragma unroll
        for (int ow = 0; ow < 3; ++ow)
          outb[oh * 9 + ow] =
              us2f(k1T[((oh + 3) * 9 + (ow + 3)) * PITCH + 4 + ch]);
      }
    }
  } else {
    if (s4 < 3) {
      int oh = s4;  // rows 0..2: k1 where ow<6, else 0
#pragma unroll
      for (int ow = 0; ow < 9; ++ow) {
        float v2 = 0.f;
        if (ow < 6)
          v2 = us2f(k1T[((oh + 3) * 9 + (ow + 3)) * PITCH + 4 + ch]);
        outb[oh * 9 + ow] = v2;
      }
    } else {
      // rows 6..8, cols 0..2: zero
#pragma unroll
      for (int r0 = 0; r0 < 3; ++r0) {
        int oh = 6 + r0;
        outb[oh * 9 + 0] = 0.f;
        outb[oh * 9 + 1] = 0.f;
        outb[oh * 9 + 2] = 0.f;
      }
    }
  }
}

extern "C" void kernel_launch(void* const* d_in, const int* in_sizes, int n_in,
                              void* d_out, int out_size, void* d_ws, size_t ws_size,
                              hipStream_t stream) {
  const float* x     = (const float*)d_in[0];
  const float* wk    = (const float*)d_in[1];
  const float* bk    = (const float*)d_in[2];
  const float* w1    = (const float*)d_in[3];
  const float* gamma = (const float*)d_in[4];
  const float* beta  = (const float*)d_in[5];
  const float* mean  = (const float*)d_in[6];
  const float* var   = (const float*)d_in[7];
  const float* w2    = (const float*)d_in[8];
  const float* b2    = (const float*)d_in[9];
  const float* wv    = (const float*)d_in[10];
  const float* bv    = (const float*)d_in[11];
  float* out = (float*)d_out;

  hipLaunchKernelGGL(semca_fused, dim3(256), dim3(1024), 0, stream,
                     x, wk, bk, w1, gamma, beta, mean, var, w2, b2, wv, bv, out);
}